// Round 4
// baseline (49.245 us; speedup 1.0000x reference)
//
#include <hip/hip_runtime.h>
#include <math.h>

// Problem geometry (fixed by the reference).
constexpr int Bc = 32, Fc = 513, Tc = 1600;
constexpr int BLK = 128;                  // threads per block (2 waves)
constexpr int VEC = 4;                    // float4 per thread
constexpr int TT  = BLK * VEC;            // 512 t per block tile
constexpr int NTT = (Tc + TT - 1) / TT;   // 4 t-tiles (last partial: 64)
constexpr int FCH = 27;                   // f rows per block (513 = 19*27)
constexpr int NFC = Fc / FCH;             // 19 f-chunks (exact)
constexpr int NBLK = Bc * NFC * NTT;      // 2432 blocks
constexpr long long NTOT = (long long)Bc * Fc * Tc;  // 26,265,600

typedef float f32x2 __attribute__((ext_vector_type(2)));

// Packed fp32 ops (VOP3P, gfx90a+). Non-volatile pure dataflow: scheduler free.
__device__ __forceinline__ f32x2 pk_fma(f32x2 a, f32x2 b, f32x2 c) {
    f32x2 d;
    asm("v_pk_fma_f32 %0, %1, %2, %3" : "=v"(d) : "v"(a), "v"(b), "v"(c));
    return d;
}
__device__ __forceinline__ f32x2 pk_add(f32x2 a, f32x2 b) {
    f32x2 d;
    asm("v_pk_add_f32 %0, %1, %2" : "=v"(d) : "v"(a), "v"(b));
    return d;
}

// Magic-add round-to-nearest-even: RNE(y) = (y + 12582912.f) - 12582912.f
// for |y| < 2^22. Here y = x/(2pi), |x| <~ 40 -> |y| <~ 7. Matches rintf/jnp.round.
#define INV2PI 0.15915494309189535f
#define MAGICF 12582912.0f
#define N2PI  -6.283185307179586f

// acc pair += |x - 2pi*RNE(x/2pi)| for both halves; abs folds into v_add modifier.
__device__ __forceinline__ void aw_acc(f32x2 x, float& sA, float& sB,
                                       f32x2 cinv, f32x2 cmag, f32x2 cnmag,
                                       f32x2 cn2pi) {
    f32x2 y = pk_fma(x, cinv, cmag);   // y = x*inv2pi + MAGIC
    f32x2 r = pk_add(y, cnmag);        // r = RNE(x*inv2pi)
    f32x2 w = pk_fma(r, cn2pi, x);     // w = x - 2pi*r
    sA += fabsf(w.x);                  // v_add_f32 with abs modifier
    sB += fabsf(w.y);
}

// Reduce three per-thread floats across the block; result valid in thread 0.
__device__ __forceinline__ void block_reduce3(float& a, float& b, float& c) {
    #pragma unroll
    for (int off = 32; off > 0; off >>= 1) {
        a += __shfl_down(a, off);
        b += __shfl_down(b, off);
        c += __shfl_down(c, off);
    }
    __shared__ float sm[3][BLK / 64];
    const int lane = threadIdx.x & 63, wid = threadIdx.x >> 6;
    if (lane == 0) { sm[0][wid] = a; sm[1][wid] = b; sm[2][wid] = c; }
    __syncthreads();
    if (threadIdx.x == 0) {
        a = sm[0][0]; b = sm[1][0]; c = sm[2][0];
        #pragma unroll
        for (int w = 1; w < BLK / 64; ++w) {
            a += sm[0][w]; b += sm[1][w]; c += sm[2][w];
        }
    }
}

__global__ __launch_bounds__(BLK) void phase_main(
        const float* __restrict__ pr, const float* __restrict__ pg,
        float* __restrict__ partials,   // [3][NBLK] when two-stage
        float* __restrict__ out,        // atomic fallback target
        int use_atomic)
{
    const int tile = blockIdx.x;   // t tile
    const int fc   = blockIdx.y;   // f chunk
    const int b    = blockIdx.z;   // batch
    const int t0   = tile * TT + (int)threadIdx.x * VEC;
    const int f0   = fc * FCH;
    const int f1   = f0 + FCH;     // 513 = 19*27 exact
    const int lane = (int)threadIdx.x & 63;
    const bool edge = (lane == 0) && (t0 > 0);

    const f32x2 cneg1 = {-1.0f, -1.0f};
    const f32x2 cinv  = {INV2PI, INV2PI};
    const f32x2 cmag  = {MAGICF, MAGICF};
    const f32x2 cnmag = {-MAGICF, -MAGICF};
    const f32x2 cn2pi = {N2PI, N2PI};

    float ipA = 0.f, ipB = 0.f, gdA = 0.f, gdB = 0.f, ptA = 0.f, ptB = 0.f;

    if (t0 < Tc) {  // Tc % VEC == 0: a thread's 4 elems are all-valid or none
        const size_t baseb = (size_t)b * Fc * Tc + (size_t)t0;
        const float* ap = pr + baseb + (size_t)f0 * Tc;
        const float* gp = pg + baseb + (size_t)f0 * Tc;

        // Previous-row d (f-1 neighbor), carried in register pairs.
        f32x2 pd01, pd23;
        if (f0 == 0) {
            pd01 = (f32x2){0.f, 0.f}; pd23 = (f32x2){0.f, 0.f};
        } else {
            float4 a = *(const float4*)(ap - Tc);
            float4 g = *(const float4*)(gp - Tc);
            pd01 = (f32x2){a.x - g.x, a.y - g.y};
            pd23 = (f32x2){a.z - g.z, a.w - g.w};
        }

        // Depth-2 software pipeline: rows f (C) and f+1 (N) resident, row f+2
        // being fetched each iteration (clamped pointer, no branch).
        float4 aC = *(const float4*)ap;
        float4 gC = *(const float4*)gp;
        float4 aN = *(const float4*)(ap + Tc);
        float4 gN = *(const float4*)(gp + Tc);
        float amC = 0.f, gmC = 0.f, amN = 0.f, gmN = 0.f;
        if (edge) {
            amC = ap[-1];      gmC = gp[-1];
            amN = ap[Tc - 1];  gmN = gp[Tc - 1];
        }

        #pragma unroll 3
        for (int f = f0; f < f1; ++f) {
            // Prefetch row f+2, clamped (re-read of row f: L1 hit, discarded).
            const bool ok = (f + 2 < f1);
            const float* ap2 = ok ? (ap + 2 * (size_t)Tc) : ap;
            const float* gp2 = ok ? (gp + 2 * (size_t)Tc) : gp;
            float4 aP = *(const float4*)ap2;
            float4 gP = *(const float4*)gp2;
            float amP = 0.f, gmP = 0.f;
            if (edge) { amP = ap2[-1]; gmP = gp2[-1]; }

            // d = a - g (packed)
            f32x2 a01 = {aC.x, aC.y}, a23 = {aC.z, aC.w};
            f32x2 g01 = {gC.x, gC.y}, g23 = {gC.z, gC.w};
            f32x2 d01 = pk_fma(g01, cneg1, a01);
            f32x2 d23 = pk_fma(g23, cneg1, a23);

            float dwm = __shfl_up(d23.y, 1);            // lane l-1's d[3]
            float dm1 = (lane == 0) ? (amC - gmC) : dwm; // 0 at global t==0

            f32x2 sh01 = {dm1, d01.x};
            f32x2 sh23 = {d01.y, d23.x};
            f32x2 pdd01 = pk_fma(d01, cneg1, pd01);      // d[f-1] - d[f]
            f32x2 pdd23 = pk_fma(d23, cneg1, pd23);
            f32x2 tdd01 = pk_fma(d01, cneg1, sh01);      // d[t-1] - d[t]
            f32x2 tdd23 = pk_fma(d23, cneg1, sh23);

            aw_acc(d01,  ipA, ipB, cinv, cmag, cnmag, cn2pi);
            aw_acc(d23,  ipA, ipB, cinv, cmag, cnmag, cn2pi);
            aw_acc(pdd01, gdA, gdB, cinv, cmag, cnmag, cn2pi);
            aw_acc(pdd23, gdA, gdB, cinv, cmag, cnmag, cn2pi);
            aw_acc(tdd01, ptA, ptB, cinv, cmag, cnmag, cn2pi);
            aw_acc(tdd23, ptA, ptB, cinv, cmag, cnmag, cn2pi);

            pd01 = d01; pd23 = d23;
            aC = aN; gC = gN; amC = amN; gmC = gmN;
            aN = aP; gN = gP; amN = amP; gmN = gmP;
            ap += Tc; gp += Tc;
        }
    }

    float s_ip = ipA + ipB, s_gd = gdA + gdB, s_ptd = ptA + ptB;
    block_reduce3(s_ip, s_gd, s_ptd);

    if (threadIdx.x == 0) {
        if (use_atomic) {
            const float invN = (float)(1.0 / (double)NTOT);
            atomicAdd(out + 0, s_ip * invN);
            atomicAdd(out + 1, s_gd * invN);
            atomicAdd(out + 2, s_ptd * invN);
        } else {
            const int bid = (blockIdx.z * gridDim.y + blockIdx.y) * gridDim.x
                          + blockIdx.x;
            partials[0 * NBLK + bid] = s_ip;
            partials[1 * NBLK + bid] = s_gd;
            partials[2 * NBLK + bid] = s_ptd;
        }
    }
}

// One block per channel; block reduces NBLK partials.
__global__ __launch_bounds__(256) void phase_reduce(
        const float* __restrict__ partials, float* __restrict__ out)
{
    const int c = blockIdx.x;
    const int tid = threadIdx.x;
    float s = 0.f;
    for (int i = tid; i < NBLK; i += 256) s += partials[(size_t)c * NBLK + i];
    #pragma unroll
    for (int off = 32; off > 0; off >>= 1) s += __shfl_down(s, off);
    __shared__ float sm[4];
    const int lane = tid & 63, wid = tid >> 6;
    if (lane == 0) sm[wid] = s;
    __syncthreads();
    if (tid == 0) {
        float t = sm[0] + sm[1] + sm[2] + sm[3];
        out[c] = t * (float)(1.0 / (double)NTOT);
    }
}

__global__ void zero3(float* out) {
    if (threadIdx.x < 3) out[threadIdx.x] = 0.f;
}

extern "C" void kernel_launch(void* const* d_in, const int* in_sizes, int n_in,
                              void* d_out, int out_size, void* d_ws, size_t ws_size,
                              hipStream_t stream) {
    const float* pr = (const float*)d_in[0];
    const float* pg = (const float*)d_in[1];
    float* out = (float*)d_out;
    dim3 grid(NTT, NFC, Bc);

    if (ws_size >= (size_t)NBLK * 3 * sizeof(float)) {
        float* partials = (float*)d_ws;
        phase_main<<<grid, BLK, 0, stream>>>(pr, pg, partials, nullptr, 0);
        phase_reduce<<<3, 256, 0, stream>>>(partials, out);
    } else {
        zero3<<<1, 64, 0, stream>>>(out);
        phase_main<<<grid, BLK, 0, stream>>>(pr, pg, nullptr, out, 1);
    }
}

// Round 5
// 47.404 us; speedup vs baseline: 1.0388x; 1.0388x over previous
//
#include <hip/hip_runtime.h>
#include <math.h>

// Problem geometry (fixed by the reference).
constexpr int Bc = 32, Fc = 513, Tc = 1600;
constexpr int FCH = 8;                  // f rows per strip
constexpr int SPB = 65;                 // strips per batch: 64 full + 1 single-row
constexpr int NSTRIP = Bc * SPB;        // 2080 strips == waves
constexpr int WPB = 4;                  // waves per block
constexpr int BLK = 64 * WPB;           // 256 threads
constexpr int NBLK = NSTRIP / WPB;      // 520 blocks (exact)
constexpr long long NTOT = (long long)Bc * Fc * Tc;  // 26,265,600

typedef float f32x2 __attribute__((ext_vector_type(2)));

// Packed fp32 VOP3P ops.
__device__ __forceinline__ f32x2 pk_fma(f32x2 a, f32x2 b, f32x2 c) {
    f32x2 d;
    asm("v_pk_fma_f32 %0, %1, %2, %3" : "=v"(d) : "v"(a), "v"(b), "v"(c));
    return d;
}
__device__ __forceinline__ f32x2 pk_add(f32x2 a, f32x2 b) {
    f32x2 d;
    asm("v_pk_add_f32 %0, %1, %2" : "=v"(d) : "v"(a), "v"(b));
    return d;
}
__device__ __forceinline__ f32x2 pk_mul(f32x2 a, f32x2 b) {
    f32x2 d;
    asm("v_pk_mul_f32 %0, %1, %2" : "=v"(d) : "v"(a), "v"(b));
    return d;
}

// Magic-add RNE round: RNE(y) = (y + 12582912.f) - 12582912.f for |y| < 2^22.
// y = x/(2pi), |x| <~ 40 here. Matches rintf / jnp.round (verified R4, absmax 0).
#define INV2PI 0.15915494309189535f
#define MAGICF 12582912.0f
#define N2PI  -6.283185307179586f

__device__ __forceinline__ void aw_acc(f32x2 x, float& sA, float& sB,
                                       f32x2 cinv, f32x2 cmag, f32x2 cnmag,
                                       f32x2 cn2pi) {
    f32x2 y = pk_fma(x, cinv, cmag);   // x*inv2pi + MAGIC
    f32x2 r = pk_add(y, cnmag);        // RNE(x*inv2pi)
    f32x2 w = pk_fma(r, cn2pi, x);     // x - 2pi*r
    sA += fabsf(w.x);                  // abs folds into v_add modifier
    sB += fabsf(w.y);
}

__global__ __launch_bounds__(BLK) void phase_main(
        const float* __restrict__ pr, const float* __restrict__ pg,
        float* __restrict__ partials,   // [3][NBLK] when two-stage
        float* __restrict__ out,        // atomic fallback target
        int use_atomic)
{
    const int lane = (int)threadIdx.x & 63;
    const int wv   = (int)blockIdx.x * WPB + ((int)threadIdx.x >> 6);
    const int b    = wv / SPB;
    const int k    = wv - b * SPB;
    const int f0   = k * FCH;
    const int len  = (k == SPB - 1) ? 1 : FCH;   // last strip is 1 row (f=512)

    const size_t rowbase = ((size_t)b * Fc + (size_t)f0) * Tc;
    const float* ap = pr + rowbase;
    const float* gp = pg + rowbase;

    const f32x2 cneg1 = {-1.0f, -1.0f};
    const f32x2 cinv  = {INV2PI, INV2PI};
    const f32x2 cmag  = {MAGICF, MAGICF};
    const f32x2 cnmag = {-MAGICF, -MAGICF};
    const f32x2 cn2pi = {N2PI, N2PI};
    const float mtail = (lane < 16) ? 1.0f : 0.0f;  // chunk-6 validity mask
    const f32x2 m2    = {mtail, mtail};

    float ipA = 0.f, ipB = 0.f, gdA = 0.f, gdB = 0.f, ptA = 0.f, ptB = 0.f;

    // Row layout per wave: chunk c covers t = c*256 + lane*4 .. +3, c = 0..5 full,
    // c = 6 valid only for lane < 16 (t 1536..1599).
    float4 A[7], G[7], Dc[7], Dp[7];

    auto load_row = [&](const float* p, float4* R) {
        #pragma unroll
        for (int c = 0; c < 6; ++c)
            R[c] = *(const float4*)(p + c * 256 + lane * 4);
        if (lane < 16) R[6] = *(const float4*)(p + 1536 + lane * 4);
        else           R[6] = make_float4(0.f, 0.f, 0.f, 0.f);
    };
    auto diff7 = [&](float4* D, const float4* X, const float4* Y) {
        #pragma unroll
        for (int c = 0; c < 7; ++c) {
            f32x2 x01 = {X[c].x, X[c].y}, x23 = {X[c].z, X[c].w};
            f32x2 y01 = {Y[c].x, Y[c].y}, y23 = {Y[c].z, Y[c].w};
            f32x2 d01 = pk_fma(y01, cneg1, x01);
            f32x2 d23 = pk_fma(y23, cneg1, x23);
            D[c] = make_float4(d01.x, d01.y, d23.x, d23.y);
        }
    };
    // Accumulate the three losses for one row: D = d(f), P = d(f-1).
    auto acc_row = [&](const float4* D, const float4* P) {
        #pragma unroll
        for (int c = 0; c < 7; ++c) {
            f32x2 d01 = {D[c].x, D[c].y}, d23 = {D[c].z, D[c].w};
            f32x2 p01 = {P[c].x, P[c].y}, p23 = {P[c].z, P[c].w};
            float up    = __shfl_up(D[c].w, 1);
            float carry = (c == 0) ? 0.f : __shfl(D[c - 1].w, 63);
            float dm1   = (lane == 0) ? carry : up;   // d[t-1], 0 at t==0
            f32x2 sh01 = {dm1, D[c].x};
            f32x2 sh23 = {D[c].y, D[c].z};
            f32x2 pdd01 = pk_fma(d01, cneg1, p01);    // d[f-1]-d[f]
            f32x2 pdd23 = pk_fma(d23, cneg1, p23);
            f32x2 tdd01 = pk_fma(d01, cneg1, sh01);   // d[t-1]-d[t]
            f32x2 tdd23 = pk_fma(d23, cneg1, sh23);
            if (c == 6) {  // lanes>=16: d==0 already, but tdd.x would leak dm1
                tdd01 = pk_mul(tdd01, m2);
                tdd23 = pk_mul(tdd23, m2);
            }
            aw_acc(d01,  ipA, ipB, cinv, cmag, cnmag, cn2pi);
            aw_acc(d23,  ipA, ipB, cinv, cmag, cnmag, cn2pi);
            aw_acc(pdd01, gdA, gdB, cinv, cmag, cnmag, cn2pi);
            aw_acc(pdd23, gdA, gdB, cinv, cmag, cnmag, cn2pi);
            aw_acc(tdd01, ptA, ptB, cinv, cmag, cnmag, cn2pi);
            aw_acc(tdd23, ptA, ptB, cinv, cmag, cnmag, cn2pi);
        }
    };

    // Prologue: row f0 and (if any) boundary row f0-1.
    load_row(ap, A);
    load_row(gp, G);
    if (f0 > 0) {
        float4 Pa[7], Pg[7];
        load_row(ap - Tc, Pa);
        load_row(gp - Tc, Pg);
        diff7(Dp, Pa, Pg);
    } else {
        #pragma unroll
        for (int c = 0; c < 7; ++c) Dp[c] = make_float4(0.f, 0.f, 0.f, 0.f);
    }
    diff7(Dc, A, G);

    if (len == 1) {
        acc_row(Dc, Dp);
    } else {
        // Ping-pong Dc/Dp roles; loads for the next row issue before the
        // current row's ~600cy of accumulation (true depth-1 row pipeline,
        // 14 independent 1KB loads in flight, no register rotation).
        for (int i = 0; i < FCH; i += 2) {
            const size_t o1 = (size_t)min(i + 1, FCH - 1) * Tc;
            load_row(ap + o1, A);
            load_row(gp + o1, G);
            acc_row(Dc, Dp);          // row i (prev = row i-1)
            diff7(Dp, A, G);          // Dp <- d(row i+1)
            const size_t o2 = (size_t)min(i + 2, FCH - 1) * Tc;
            load_row(ap + o2, A);
            load_row(gp + o2, G);
            acc_row(Dp, Dc);          // row i+1 (prev = row i)
            diff7(Dc, A, G);          // Dc <- d(row i+2) (clamped junk on last)
        }
    }

    // Block reduction across 4 waves.
    float s_ip = ipA + ipB, s_gd = gdA + gdB, s_ptd = ptA + ptB;
    #pragma unroll
    for (int off = 32; off > 0; off >>= 1) {
        s_ip  += __shfl_down(s_ip, off);
        s_gd  += __shfl_down(s_gd, off);
        s_ptd += __shfl_down(s_ptd, off);
    }
    __shared__ float sm[3][WPB];
    const int wid = (int)threadIdx.x >> 6;
    if (lane == 0) { sm[0][wid] = s_ip; sm[1][wid] = s_gd; sm[2][wid] = s_ptd; }
    __syncthreads();
    if (threadIdx.x == 0) {
        float a = 0.f, bb = 0.f, c = 0.f;
        #pragma unroll
        for (int w = 0; w < WPB; ++w) { a += sm[0][w]; bb += sm[1][w]; c += sm[2][w]; }
        if (use_atomic) {
            const float invN = (float)(1.0 / (double)NTOT);
            atomicAdd(out + 0, a * invN);
            atomicAdd(out + 1, bb * invN);
            atomicAdd(out + 2, c * invN);
        } else {
            partials[0 * NBLK + blockIdx.x] = a;
            partials[1 * NBLK + blockIdx.x] = bb;
            partials[2 * NBLK + blockIdx.x] = c;
        }
    }
}

// One block per channel; reduces NBLK partials.
__global__ __launch_bounds__(256) void phase_reduce(
        const float* __restrict__ partials, float* __restrict__ out)
{
    const int c = blockIdx.x;
    const int tid = threadIdx.x;
    float s = 0.f;
    for (int i = tid; i < NBLK; i += 256) s += partials[(size_t)c * NBLK + i];
    #pragma unroll
    for (int off = 32; off > 0; off >>= 1) s += __shfl_down(s, off);
    __shared__ float sm[4];
    const int lane = tid & 63, wid = tid >> 6;
    if (lane == 0) sm[wid] = s;
    __syncthreads();
    if (tid == 0) {
        float t = sm[0] + sm[1] + sm[2] + sm[3];
        out[c] = t * (float)(1.0 / (double)NTOT);
    }
}

__global__ void zero3(float* out) {
    if (threadIdx.x < 3) out[threadIdx.x] = 0.f;
}

extern "C" void kernel_launch(void* const* d_in, const int* in_sizes, int n_in,
                              void* d_out, int out_size, void* d_ws, size_t ws_size,
                              hipStream_t stream) {
    const float* pr = (const float*)d_in[0];
    const float* pg = (const float*)d_in[1];
    float* out = (float*)d_out;

    if (ws_size >= (size_t)NBLK * 3 * sizeof(float)) {
        float* partials = (float*)d_ws;
        phase_main<<<NBLK, BLK, 0, stream>>>(pr, pg, partials, nullptr, 0);
        phase_reduce<<<3, 256, 0, stream>>>(partials, out);
    } else {
        zero3<<<1, 64, 0, stream>>>(out);
        phase_main<<<NBLK, BLK, 0, stream>>>(pr, pg, nullptr, out, 1);
    }
}